// Round 15
// baseline (223.657 us; speedup 1.0000x reference)
//
#include <hip/hip_runtime.h>
#include <hip/hip_fp8.h>

#define BB 8
#define NN 4096
#define MM 4096
#define DD 128

typedef float f32x4 __attribute__((ext_vector_type(4)));
typedef long  long2v __attribute__((ext_vector_type(2)));

// ---------------------------------------------------------------------------
// Fragment-ordered fp8 layout (verified R7-R13, absmax 0): for 16-row group
// g, K-half h, the 1KB unit holds lane(quad,l15) -> 16B: row=l15 (in group),
// k=(2h+p)*32+quad*8+(0..7) at byte p*8+(k&7).
//
// LESSON (R11/R12): __threadfence() (acquire+release, -> buffer_inv) in every
// block invalidates the XCD L2 under all resident blocks -> 8x regression.
// Merged finalize here uses RELEASE-only counter RMW per block (writeback of
// ~zero dirty lines, no invalidate) + ACQUIRE in the single last block.
// LESSON (R14): hipLaunchCooperativeKernel fails under this harness. Don't.
// ---------------------------------------------------------------------------

// Prep: one row per 32 lanes, float4/thread, HW packed fp8 convert
// (v_cvt_pk_fp8_f32), exact fp32 norms via shfl, scattered 4B
// fragment-ordered stores. Also inits fwd/bsum/counter.
__global__ __launch_bounds__(256)
void prep_all(const float* __restrict__ x, const float* __restrict__ y,
              unsigned char* __restrict__ xq, unsigned char* __restrict__ yq,
              float* __restrict__ x2, float* __restrict__ y2,
              unsigned int* __restrict__ fwd, float* __restrict__ bsum,
              unsigned int* __restrict__ counter) {
    int gtid = blockIdx.x * blockDim.x + threadIdx.x;
    if (gtid < BB * MM) fwd[gtid] = 0x7f800000u;  // +inf bits
    if (gtid == 0) { *bsum = 0.0f; *counter = 0u; }

    int row = gtid >> 5;
    int k4  = gtid & 31;
    const float* src;
    unsigned char* dst;
    float* sq;
    if (row < BB * NN) {
        src = x; dst = xq; sq = x2;
    } else {
        src = y; dst = yq; sq = y2; row -= BB * NN;
    }
    f32x4 v = ((const f32x4*)src)[(size_t)row * 32 + k4];
    float s = v.x * v.x + v.y * v.y + v.z * v.z + v.w * v.w;
    unsigned int p32 = (unsigned int)__builtin_amdgcn_cvt_pk_fp8_f32(v.x, v.y, 0, false);
    p32 = (unsigned int)__builtin_amdgcn_cvt_pk_fp8_f32(v.z, v.w, (int)p32, true);

    int k    = k4 << 2;
    int kk   = k >> 5;
    int h    = kk >> 1;
    int p    = kk & 1;
    int quad = (k >> 3) & 3;
    size_t dstoff = ((size_t)(row >> 4) * 2 + h) * 1024
                  + (size_t)(quad * 16 + (row & 15)) * 16 + p * 8 + (k & 7);
    *(unsigned int*)(dst + dstoff) = p32;

    #pragma unroll
    for (int m = 16; m; m >>= 1) s += __shfl_xor(s, m, 64);  // stays in 32-half
    if (k4 == 0) sq[row] = s;
}

// ---------------------------------------------------------------------------
// Main: EXACT R13/R10 hot loop (51-54us, VGPR 64, 8 waves/SIMD, fence-free).
// Tail: backward partial -> device atomicAdd (no dirty stores), then
// RELEASE counter RMW; single last block ACQUIREs and reduces fwd (128 KB,
// L2/L3-resident) + writes out. Two launches total.
// ---------------------------------------------------------------------------
__global__ __launch_bounds__(256, 4)
void chamfer_main(const unsigned char* __restrict__ xq, const unsigned char* __restrict__ yq,
                  const float* __restrict__ x2, const float* __restrict__ y2,
                  unsigned int* __restrict__ fwd, float* __restrict__ bsum,
                  unsigned int* __restrict__ counter, float* __restrict__ out) {
    __shared__ float x2s[BB][128];          // 4 KB
    __shared__ float y2s[BB][32];           // 1 KB
    __shared__ unsigned int fbuf[BB][32];   // 1 KB
    __shared__ float red[4];
    __shared__ int isLast;

    const int tid  = threadIdx.x;
    const int lane = tid & 63;
    const int wave = tid >> 6;
    const int quad = lane >> 4;
    const int l15  = lane & 15;

    // 4096 blocks; per-XCD m-stripe: xcd = id&7 -> mb = xcd*16 + (j>>5)
    const int id  = blockIdx.x;
    const int xcd = id & 7;
    const int j   = id >> 3;                 // 0..511
    const int nb  = j & 31;                  // 0..31 (128 n each)
    const int mb  = xcd * 16 + (j >> 5);     // 0..127 (32 m each)
    const int n0b = nb * 128;
    const int n0w = n0b + wave * 32;
    const int m0  = mb * 32;

    const size_t lane16 = (size_t)lane * 16;
    const unsigned char* xbase = xq + (size_t)(n0w >> 4) * 2048 + lane16;
    const unsigned char* ybase = yq + (size_t)(m0 >> 4) * 2048 + lane16;

    // stage norms + init fbuf (once), then the only pre-loop barrier
    for (int i = tid; i < BB * 128; i += 256)
        x2s[i >> 7][i & 127] = x2[(size_t)(i >> 7) * NN + n0b + (i & 127)];
    if (tid < BB * 32) {
        y2s[tid >> 5][tid & 31] = y2[(size_t)(tid >> 5) * MM + m0 + (tid & 31)];
        ((unsigned int*)fbuf)[tid] = 0x7f800000u;
    }
    __syncthreads();

    long2v fx[2][2][2], fy[2][2][2];  // [buf][group][half]
    auto loadb = [&](int b, int s) {
        const unsigned char* xb = xbase + ((size_t)b << 19);  // b*256 groups*2KB
        const unsigned char* yb = ybase + ((size_t)b << 19);
        #pragma unroll
        for (int g2 = 0; g2 < 2; ++g2)
            #pragma unroll
            for (int h = 0; h < 2; ++h) {
                fx[s][g2][h] = *(const long2v*)(xb + ((g2 * 2 + h) << 10));
                fy[s][g2][h] = *(const long2v*)(yb + ((g2 * 2 + h) << 10));
            }
    };
    loadb(0, 0);

    const float INF = __builtin_inff();
    f32x4 bmin[2][2];
    #pragma unroll
    for (int fi = 0; fi < 2; ++fi)
        #pragma unroll
        for (int fj = 0; fj < 2; ++fj)
            bmin[fi][fj] = (f32x4){INF, INF, INF, INF};

    #pragma unroll 2
    for (int b = 0; b < BB; ++b) {
        const int cur = b & 1;
        if (b < BB - 1) loadb(b + 1, cur ^ 1);  // the ONLY vmem in the loop

        f32x4 acc[2][2];
        #pragma unroll
        for (int fi = 0; fi < 2; ++fi)
            #pragma unroll
            for (int fj = 0; fj < 2; ++fj)
                acc[fi][fj] = (f32x4){0.f, 0.f, 0.f, 0.f};

        #pragma unroll
        for (int h = 0; h < 2; ++h)
            #pragma unroll
            for (int p = 0; p < 2; ++p)
                #pragma unroll
                for (int fi = 0; fi < 2; ++fi)
                    #pragma unroll
                    for (int fj = 0; fj < 2; ++fj)
                        acc[fi][fj] = __builtin_amdgcn_mfma_f32_16x16x32_fp8_fp8(
                            fx[cur][fi][h][p], fy[cur][fj][h][p], acc[fi][fj], 0, 0, 0);

        // epilogue on SQUARED distances; norms from LDS; NO shfl, NO branch
        float y2v[2];
        y2v[0] = y2s[b][l15];
        y2v[1] = y2s[b][16 + l15];
        float fm[2] = {INF, INF};
        #pragma unroll
        for (int fi = 0; fi < 2; ++fi) {
            const f32x4 x2v = *(const f32x4*)&x2s[b][wave * 32 + fi * 16 + quad * 4];
            #pragma unroll
            for (int fj = 0; fj < 2; ++fj)
                #pragma unroll
                for (int e = 0; e < 4; ++e) {
                    float sqv = fmaf(-2.0f, acc[fi][fj][e], x2v[e] + y2v[fj]);
                    bmin[fi][fj][e] = fminf(bmin[fi][fj][e], sqv);
                    fm[fj]          = fminf(fm[fj], sqv);
                }
        }
        #pragma unroll
        for (int fj = 0; fj < 2; ++fj) {
            // 4 quads same address: no-return ds_min, pipelined, no chain
            atomicMin(&fbuf[b][fj * 16 + l15],
                      __float_as_uint(fmaxf(fm[fj], 0.0f)));
        }
    }
    __syncthreads();  // all waves' fbuf contributions visible

    // flush forward mins: 256 entries, one per thread (device-scope atomics)
    {
        int b = tid >> 5, c = tid & 31;
        atomicMin(&fwd[(size_t)b * MM + m0 + c], fbuf[b][c]);
    }

    // backward: sqrt(clamp(min-over-b)), block-reduce, device atomicAdd
    // (atomic, not a plain store -> no dirty L2 lines for the release below)
    float s = 0.0f;
    #pragma unroll
    for (int fi = 0; fi < 2; ++fi)
        #pragma unroll
        for (int fj = 0; fj < 2; ++fj)
            #pragma unroll
            for (int e = 0; e < 4; ++e)
                s += sqrtf(fmaxf(bmin[fi][fj][e], 0.0f));
    #pragma unroll
    for (int off = 32; off; off >>= 1) s += __shfl_down(s, off, 64);
    if (lane == 0) red[wave] = s;
    __syncthreads();

    // merged finalize: RELEASE-only counter bump per block (no invalidate);
    // ACQUIRE + plain reduction in the single last block.
    if (tid == 0) {
        atomicAdd(bsum, red[0] + red[1] + red[2] + red[3]);
        unsigned int c = __hip_atomic_fetch_add(counter, 1u, __ATOMIC_RELEASE,
                                                __HIP_MEMORY_SCOPE_AGENT);
        isLast = (c == 4095u) ? 1 : 0;
    }
    __syncthreads();
    if (isLast) {
        if (tid == 0)  // one acquire: invalidates this CU/XCD's stale lines
            (void)__hip_atomic_load(counter, __ATOMIC_ACQUIRE,
                                    __HIP_MEMORY_SCOPE_AGENT);
        __syncthreads();
        float sf = 0.0f;
        const uint4* fw4 = (const uint4*)fwd;
        for (int i = tid; i < (BB * MM) / 4; i += 256) {
            uint4 u = fw4[i];
            sf += sqrtf(__uint_as_float(u.x)) + sqrtf(__uint_as_float(u.y)) +
                  sqrtf(__uint_as_float(u.z)) + sqrtf(__uint_as_float(u.w));
        }
        #pragma unroll
        for (int off = 32; off; off >>= 1) sf += __shfl_down(sf, off, 64);
        if (lane == 0) red[wave] = sf;
        __syncthreads();
        if (tid == 0) {
            float ftot = red[0] + red[1] + red[2] + red[3];
            float bs = __hip_atomic_load(bsum, __ATOMIC_RELAXED,
                                         __HIP_MEMORY_SCOPE_AGENT);
            out[0] = ftot / (float)(BB * MM) + bs / ((float)NN * (float)MM);
        }
    }
}

extern "C" void kernel_launch(void* const* d_in, const int* in_sizes, int n_in,
                              void* d_out, int out_size, void* d_ws, size_t ws_size,
                              hipStream_t stream) {
    const float* x = (const float*)d_in[0];  // (B,N,D)
    const float* y = (const float*)d_in[1];  // (B,M,D)
    float* out = (float*)d_out;

    char* w = (char*)d_ws;
    unsigned char* xq = (unsigned char*)(w);               // 4 MB fp8 (frag order)
    unsigned char* yq = (unsigned char*)(w + 4194304);     // 4 MB fp8 (frag order)
    float*    x2 = (float*)(w + 8388608);                  // 128 KB
    float*    y2 = (float*)(w + 8519680);                  // 128 KB
    unsigned int* fwd = (unsigned int*)(w + 8650752);      // 128 KB
    float*    bsum = (float*)(w + 8781824);                // 4 B
    unsigned int* counter = (unsigned int*)(w + 8781828);  // 4 B

    // 65536 rows, one per 32 lanes -> 2M threads
    prep_all<<<(2 * BB * NN * 32) / 256, 256, 0, stream>>>(x, y, xq, yq, x2, y2,
                                                           fwd, bsum, counter);
    chamfer_main<<<4096, 256, 0, stream>>>(xq, yq, x2, y2, fwd, bsum, counter, out);
}

// Round 16
// 198.581 us; speedup vs baseline: 1.1263x; 1.1263x over previous
//
#include <hip/hip_runtime.h>
#include <hip/hip_fp8.h>

#define BB 8
#define NN 4096
#define MM 4096
#define DD 128

typedef float f32x4 __attribute__((ext_vector_type(4)));
typedef long  long2v __attribute__((ext_vector_type(2)));

// ---------------------------------------------------------------------------
// Fragment-ordered fp8 layout (verified R7-R13, absmax 0): for 16-row group
// g, K-half h, the 1KB unit holds lane(quad,l15) -> 16B: row=l15 (in group),
// k=(2h+p)*32+quad*8+(0..7) at byte p*8+(k&7).
//
// FENCE LESSONS (R7/R11/R12/R15): per-block __threadfence (acquire+release ->
// buffer_inv) = 8x regression; per-block RELEASE RMW (buffer_wbl2) = 3x.
// ONLY fully RELAXED atomics are free per block (R10: 256 relaxed global
// atomicMin + atomicAdd per block, main 51us). This version's merged
// finalize: returning atomicMin (completion proven by the vmcnt(0) the
// compiler emits before __syncthreads) -> RELAXED counter bump; the single
// last block pays the one ACQUIRE. R14: cooperative launch fails here. Don't.
// ---------------------------------------------------------------------------

// Prep: one row per 32 lanes, float4/thread, HW packed fp8 convert
// (v_cvt_pk_fp8_f32), exact fp32 norms via shfl, scattered 4B
// fragment-ordered stores. Also inits fwd/bsum/counter.
__global__ __launch_bounds__(256)
void prep_all(const float* __restrict__ x, const float* __restrict__ y,
              unsigned char* __restrict__ xq, unsigned char* __restrict__ yq,
              float* __restrict__ x2, float* __restrict__ y2,
              unsigned int* __restrict__ fwd, float* __restrict__ bsum,
              unsigned int* __restrict__ counter) {
    int gtid = blockIdx.x * blockDim.x + threadIdx.x;
    if (gtid < BB * MM) fwd[gtid] = 0x7f800000u;  // +inf bits
    if (gtid == 0) { *bsum = 0.0f; *counter = 0u; }

    int row = gtid >> 5;
    int k4  = gtid & 31;
    const float* src;
    unsigned char* dst;
    float* sq;
    if (row < BB * NN) {
        src = x; dst = xq; sq = x2;
    } else {
        src = y; dst = yq; sq = y2; row -= BB * NN;
    }
    f32x4 v = ((const f32x4*)src)[(size_t)row * 32 + k4];
    float s = v.x * v.x + v.y * v.y + v.z * v.z + v.w * v.w;
    unsigned int p32 = (unsigned int)__builtin_amdgcn_cvt_pk_fp8_f32(v.x, v.y, 0, false);
    p32 = (unsigned int)__builtin_amdgcn_cvt_pk_fp8_f32(v.z, v.w, (int)p32, true);

    int k    = k4 << 2;
    int kk   = k >> 5;
    int h    = kk >> 1;
    int p    = kk & 1;
    int quad = (k >> 3) & 3;
    size_t dstoff = ((size_t)(row >> 4) * 2 + h) * 1024
                  + (size_t)(quad * 16 + (row & 15)) * 16 + p * 8 + (k & 7);
    *(unsigned int*)(dst + dstoff) = p32;

    #pragma unroll
    for (int m = 16; m; m >>= 1) s += __shfl_xor(s, m, 64);  // stays in 32-half
    if (k4 == 0) sq[row] = s;
}

// ---------------------------------------------------------------------------
// Main: EXACT R13/R10 hot loop (51-54us, VGPR 64, 8 waves/SIMD, fence-free).
// Tail: returning global atomicMin (fwd) + relaxed atomicAdd (bsum) ->
// __syncthreads (vmcnt(0): atomics performed at coherence point) -> RELAXED
// counter bump. Last block: one ACQUIRE, reduce fwd, write out. 2 launches.
// ---------------------------------------------------------------------------
__global__ __launch_bounds__(256, 4)
void chamfer_main(const unsigned char* __restrict__ xq, const unsigned char* __restrict__ yq,
                  const float* __restrict__ x2, const float* __restrict__ y2,
                  unsigned int* __restrict__ fwd, float* __restrict__ bsum,
                  unsigned int* __restrict__ counter, float* __restrict__ out) {
    __shared__ float x2s[BB][128];          // 4 KB
    __shared__ float y2s[BB][32];           // 1 KB
    __shared__ unsigned int fbuf[BB][32];   // 1 KB
    __shared__ float red[4];
    __shared__ int isLast;

    const int tid  = threadIdx.x;
    const int lane = tid & 63;
    const int wave = tid >> 6;
    const int quad = lane >> 4;
    const int l15  = lane & 15;

    // 4096 blocks; per-XCD m-stripe: xcd = id&7 -> mb = xcd*16 + (j>>5)
    const int id  = blockIdx.x;
    const int xcd = id & 7;
    const int j   = id >> 3;                 // 0..511
    const int nb  = j & 31;                  // 0..31 (128 n each)
    const int mb  = xcd * 16 + (j >> 5);     // 0..127 (32 m each)
    const int n0b = nb * 128;
    const int n0w = n0b + wave * 32;
    const int m0  = mb * 32;

    const size_t lane16 = (size_t)lane * 16;
    const unsigned char* xbase = xq + (size_t)(n0w >> 4) * 2048 + lane16;
    const unsigned char* ybase = yq + (size_t)(m0 >> 4) * 2048 + lane16;

    // stage norms + init fbuf (once), then the only pre-loop barrier
    for (int i = tid; i < BB * 128; i += 256)
        x2s[i >> 7][i & 127] = x2[(size_t)(i >> 7) * NN + n0b + (i & 127)];
    if (tid < BB * 32) {
        y2s[tid >> 5][tid & 31] = y2[(size_t)(tid >> 5) * MM + m0 + (tid & 31)];
        ((unsigned int*)fbuf)[tid] = 0x7f800000u;
    }
    __syncthreads();

    long2v fx[2][2][2], fy[2][2][2];  // [buf][group][half]
    auto loadb = [&](int b, int s) {
        const unsigned char* xb = xbase + ((size_t)b << 19);  // b*256 groups*2KB
        const unsigned char* yb = ybase + ((size_t)b << 19);
        #pragma unroll
        for (int g2 = 0; g2 < 2; ++g2)
            #pragma unroll
            for (int h = 0; h < 2; ++h) {
                fx[s][g2][h] = *(const long2v*)(xb + ((g2 * 2 + h) << 10));
                fy[s][g2][h] = *(const long2v*)(yb + ((g2 * 2 + h) << 10));
            }
    };
    loadb(0, 0);

    const float INF = __builtin_inff();
    f32x4 bmin[2][2];
    #pragma unroll
    for (int fi = 0; fi < 2; ++fi)
        #pragma unroll
        for (int fj = 0; fj < 2; ++fj)
            bmin[fi][fj] = (f32x4){INF, INF, INF, INF};

    #pragma unroll 2
    for (int b = 0; b < BB; ++b) {
        const int cur = b & 1;
        if (b < BB - 1) loadb(b + 1, cur ^ 1);  // the ONLY vmem in the loop

        f32x4 acc[2][2];
        #pragma unroll
        for (int fi = 0; fi < 2; ++fi)
            #pragma unroll
            for (int fj = 0; fj < 2; ++fj)
                acc[fi][fj] = (f32x4){0.f, 0.f, 0.f, 0.f};

        #pragma unroll
        for (int h = 0; h < 2; ++h)
            #pragma unroll
            for (int p = 0; p < 2; ++p)
                #pragma unroll
                for (int fi = 0; fi < 2; ++fi)
                    #pragma unroll
                    for (int fj = 0; fj < 2; ++fj)
                        acc[fi][fj] = __builtin_amdgcn_mfma_f32_16x16x32_fp8_fp8(
                            fx[cur][fi][h][p], fy[cur][fj][h][p], acc[fi][fj], 0, 0, 0);

        // epilogue on SQUARED distances; norms from LDS; NO shfl, NO branch
        float y2v[2];
        y2v[0] = y2s[b][l15];
        y2v[1] = y2s[b][16 + l15];
        float fm[2] = {INF, INF};
        #pragma unroll
        for (int fi = 0; fi < 2; ++fi) {
            const f32x4 x2v = *(const f32x4*)&x2s[b][wave * 32 + fi * 16 + quad * 4];
            #pragma unroll
            for (int fj = 0; fj < 2; ++fj)
                #pragma unroll
                for (int e = 0; e < 4; ++e) {
                    float sqv = fmaf(-2.0f, acc[fi][fj][e], x2v[e] + y2v[fj]);
                    bmin[fi][fj][e] = fminf(bmin[fi][fj][e], sqv);
                    fm[fj]          = fminf(fm[fj], sqv);
                }
        }
        #pragma unroll
        for (int fj = 0; fj < 2; ++fj) {
            // 4 quads same address: no-return ds_min, pipelined, no chain
            atomicMin(&fbuf[b][fj * 16 + l15],
                      __float_as_uint(fmaxf(fm[fj], 0.0f)));
        }
    }
    __syncthreads();  // all waves' fbuf contributions visible

    // flush forward mins: RETURNING relaxed atomicMin (one per thread).
    // dep is consumed below through a never-true compare so sc0 survives.
    unsigned int dep;
    {
        int b = tid >> 5, c = tid & 31;
        dep = atomicMin(&fwd[(size_t)b * MM + m0 + c], fbuf[b][c]);
    }

    // backward: sqrt(clamp(min-over-b)), block-reduce, relaxed atomicAdd
    float s = 0.0f;
    #pragma unroll
    for (int fi = 0; fi < 2; ++fi)
        #pragma unroll
        for (int fj = 0; fj < 2; ++fj)
            #pragma unroll
            for (int e = 0; e < 4; ++e)
                s += sqrtf(fmaxf(bmin[fi][fj][e], 0.0f));
    // never true (fwd holds clamped >=0 sq-dists or +inf=0x7f800000; NaN bits
    // 0x7f800001 are never stored) — forces the returning form & a real dep
    if (dep == 0x7f800001u) s += 1.0f;
    #pragma unroll
    for (int off = 32; off; off >>= 1) s += __shfl_down(s, off, 64);
    if (lane == 0) red[wave] = s;
    __syncthreads();  // emits s_waitcnt vmcnt(0): all fwd atomics PERFORMED

    if (tid == 0) {
        atomicAdd(bsum, red[0] + red[1] + red[2] + red[3]);
        // relaxed bump — no wbl2, no inv (the whole point)
        unsigned int c = __hip_atomic_fetch_add(counter, 1u, __ATOMIC_RELAXED,
                                                __HIP_MEMORY_SCOPE_AGENT);
        isLast = (c == 4095u) ? 1 : 0;
    }
    __syncthreads();  // vmcnt(0): bsum add performed before anyone proceeds

    if (isLast) {
        if (tid == 0)  // the ONE acquire in the grid: invalidate stale lines
            (void)__hip_atomic_load(counter, __ATOMIC_ACQUIRE,
                                    __HIP_MEMORY_SCOPE_AGENT);
        __syncthreads();
        float sf = 0.0f;
        const uint4* fw4 = (const uint4*)fwd;
        for (int i = tid; i < (BB * MM) / 4; i += 256) {
            uint4 u = fw4[i];
            sf += sqrtf(__uint_as_float(u.x)) + sqrtf(__uint_as_float(u.y)) +
                  sqrtf(__uint_as_float(u.z)) + sqrtf(__uint_as_float(u.w));
        }
        #pragma unroll
        for (int off = 32; off; off >>= 1) sf += __shfl_down(sf, off, 64);
        if (lane == 0) red[wave] = sf;
        __syncthreads();
        if (tid == 0) {
            float ftot = red[0] + red[1] + red[2] + red[3];
            float bs = __hip_atomic_load(bsum, __ATOMIC_RELAXED,
                                         __HIP_MEMORY_SCOPE_AGENT);
            out[0] = ftot / (float)(BB * MM) + bs / ((float)NN * (float)MM);
        }
    }
}

extern "C" void kernel_launch(void* const* d_in, const int* in_sizes, int n_in,
                              void* d_out, int out_size, void* d_ws, size_t ws_size,
                              hipStream_t stream) {
    const float* x = (const float*)d_in[0];  // (B,N,D)
    const float* y = (const float*)d_in[1];  // (B,M,D)
    float* out = (float*)d_out;

    char* w = (char*)d_ws;
    unsigned char* xq = (unsigned char*)(w);               // 4 MB fp8 (frag order)
    unsigned char* yq = (unsigned char*)(w + 4194304);     // 4 MB fp8 (frag order)
    float*    x2 = (float*)(w + 8388608);                  // 128 KB
    float*    y2 = (float*)(w + 8519680);                  // 128 KB
    unsigned int* fwd = (unsigned int*)(w + 8650752);      // 128 KB
    float*    bsum = (float*)(w + 8781824);                // 4 B
    unsigned int* counter = (unsigned int*)(w + 8781828);  // 4 B

    // 65536 rows, one per 32 lanes -> 2M threads
    prep_all<<<(2 * BB * NN * 32) / 256, 256, 0, stream>>>(x, y, xq, yq, x2, y2,
                                                           fwd, bsum, counter);
    chamfer_main<<<4096, 256, 0, stream>>>(xq, yq, x2, y2, fwd, bsum, counter, out);
}

// Round 17
// 120.177 us; speedup vs baseline: 1.8611x; 1.6524x over previous
//
#include <hip/hip_runtime.h>
#include <hip/hip_fp8.h>

#define BB 8
#define NN 4096
#define MM 4096
#define DD 128

typedef float f32x4 __attribute__((ext_vector_type(4)));
typedef long  long2v __attribute__((ext_vector_type(2)));

// ---------------------------------------------------------------------------
// Fragment-ordered fp8 layout (verified R7-R16, absmax 0): for 16-row group
// g, K-half h, the 1KB unit holds lane(quad,l15) -> 16B: row=l15 (in group),
// k=(2h+p)*32+quad*8+(0..7) at byte p*8+(k&7).
//
// LESSONS:
//  - R11/R12/R15/R16: ANY merged-finalize tail in the 4096-block main
//    regresses it (fences invalidate/writeback L2; even relaxed variants
//    lose ~70us). Finalize stays a separate 32-block kernel. 3 launches.
//  - R14: hipLaunchCooperativeKernel fails under this harness.
//  - R3/R4/R8/R11: explicit pipelining/sched pinning loses to compiler
//    sunk loads + 8-waves/SIMD TLP (VGPR 64 regime).
//  - R17 change: balanced per-XCD tiling (8 nb x 64 mb patch) -> per-XCD
//    working set 3MB < 4MB L2 (was 4.5MB m-stripe -> thrash, 51MB refetch).
// ---------------------------------------------------------------------------

// Prep: one row per 32 lanes, float4/thread, HW packed fp8 convert
// (v_cvt_pk_fp8_f32), exact fp32 norms via shfl, scattered 4B
// fragment-ordered stores. Also inits fwd/bsum/fsum/counter.
__global__ __launch_bounds__(256)
void prep_all(const float* __restrict__ x, const float* __restrict__ y,
              unsigned char* __restrict__ xq, unsigned char* __restrict__ yq,
              float* __restrict__ x2, float* __restrict__ y2,
              unsigned int* __restrict__ fwd, float* __restrict__ bsum,
              float* __restrict__ fsum, unsigned int* __restrict__ counter) {
    int gtid = blockIdx.x * blockDim.x + threadIdx.x;
    if (gtid < BB * MM) fwd[gtid] = 0x7f800000u;  // +inf bits
    if (gtid == 0) { *bsum = 0.0f; *fsum = 0.0f; *counter = 0u; }

    int row = gtid >> 5;
    int k4  = gtid & 31;
    const float* src;
    unsigned char* dst;
    float* sq;
    if (row < BB * NN) {
        src = x; dst = xq; sq = x2;
    } else {
        src = y; dst = yq; sq = y2; row -= BB * NN;
    }
    f32x4 v = ((const f32x4*)src)[(size_t)row * 32 + k4];
    float s = v.x * v.x + v.y * v.y + v.z * v.z + v.w * v.w;
    unsigned int p32 = (unsigned int)__builtin_amdgcn_cvt_pk_fp8_f32(v.x, v.y, 0, false);
    p32 = (unsigned int)__builtin_amdgcn_cvt_pk_fp8_f32(v.z, v.w, (int)p32, true);

    int k    = k4 << 2;
    int kk   = k >> 5;
    int h    = kk >> 1;
    int p    = kk & 1;
    int quad = (k >> 3) & 3;
    size_t dstoff = ((size_t)(row >> 4) * 2 + h) * 1024
                  + (size_t)(quad * 16 + (row & 15)) * 16 + p * 8 + (k & 7);
    *(unsigned int*)(dst + dstoff) = p32;

    #pragma unroll
    for (int m = 16; m; m >>= 1) s += __shfl_xor(s, m, 64);  // stays in 32-half
    if (k4 == 0) sq[row] = s;
}

// ---------------------------------------------------------------------------
// Main: EXACT R13 hot loop (54us, VGPR 64, 8 waves/SIMD, fence-free).
// ONLY change: balanced XCD patch (8 nb x 64 mb) so x-stripe (1MB) +
// y-stripe (2MB) fit the 4MB XCD L2 across all 8 batches.
// ---------------------------------------------------------------------------
__global__ __launch_bounds__(256, 4)
void chamfer_main(const unsigned char* __restrict__ xq, const unsigned char* __restrict__ yq,
                  const float* __restrict__ x2, const float* __restrict__ y2,
                  unsigned int* __restrict__ fwd, float* __restrict__ bpart) {
    __shared__ float x2s[BB][128];          // 4 KB
    __shared__ float y2s[BB][32];           // 1 KB
    __shared__ unsigned int fbuf[BB][32];   // 1 KB
    __shared__ float red[4];

    const int tid  = threadIdx.x;
    const int lane = tid & 63;
    const int wave = tid >> 6;
    const int quad = lane >> 4;
    const int l15  = lane & 15;

    // Balanced per-XCD patch: xcd = id&7 (hw round-robin). n-group = xcd>>1
    // (4 groups x 8 nb), m-group = xcd&1 (2 groups x 64 mb).
    // Per XCD over 8 batches: x 8*128*128B*8 = 1MB, y 64*32*128B*8 = 2MB.
    const int id  = blockIdx.x;
    const int xcd = id & 7;
    const int j   = id >> 3;                  // 0..511
    const int nb  = (xcd >> 1) * 8 + (j & 7); // 0..31 (128 n each)
    const int mb  = (xcd & 1) * 64 + (j >> 3);// 0..127 (32 m each)
    const int n0b = nb * 128;
    const int n0w = n0b + wave * 32;
    const int m0  = mb * 32;

    const size_t lane16 = (size_t)lane * 16;
    const unsigned char* xbase = xq + (size_t)(n0w >> 4) * 2048 + lane16;
    const unsigned char* ybase = yq + (size_t)(m0 >> 4) * 2048 + lane16;

    // stage norms + init fbuf (once), then the only pre-loop barrier
    for (int i = tid; i < BB * 128; i += 256)
        x2s[i >> 7][i & 127] = x2[(size_t)(i >> 7) * NN + n0b + (i & 127)];
    if (tid < BB * 32) {
        y2s[tid >> 5][tid & 31] = y2[(size_t)(tid >> 5) * MM + m0 + (tid & 31)];
        ((unsigned int*)fbuf)[tid] = 0x7f800000u;
    }
    __syncthreads();

    long2v fx[2][2][2], fy[2][2][2];  // [buf][group][half]
    auto loadb = [&](int b, int s) {
        const unsigned char* xb = xbase + ((size_t)b << 19);  // b*256 groups*2KB
        const unsigned char* yb = ybase + ((size_t)b << 19);
        #pragma unroll
        for (int g2 = 0; g2 < 2; ++g2)
            #pragma unroll
            for (int h = 0; h < 2; ++h) {
                fx[s][g2][h] = *(const long2v*)(xb + ((g2 * 2 + h) << 10));
                fy[s][g2][h] = *(const long2v*)(yb + ((g2 * 2 + h) << 10));
            }
    };
    loadb(0, 0);

    const float INF = __builtin_inff();
    f32x4 bmin[2][2];
    #pragma unroll
    for (int fi = 0; fi < 2; ++fi)
        #pragma unroll
        for (int fj = 0; fj < 2; ++fj)
            bmin[fi][fj] = (f32x4){INF, INF, INF, INF};

    #pragma unroll 2
    for (int b = 0; b < BB; ++b) {
        const int cur = b & 1;
        if (b < BB - 1) loadb(b + 1, cur ^ 1);  // the ONLY vmem in the loop

        f32x4 acc[2][2];
        #pragma unroll
        for (int fi = 0; fi < 2; ++fi)
            #pragma unroll
            for (int fj = 0; fj < 2; ++fj)
                acc[fi][fj] = (f32x4){0.f, 0.f, 0.f, 0.f};

        #pragma unroll
        for (int h = 0; h < 2; ++h)
            #pragma unroll
            for (int p = 0; p < 2; ++p)
                #pragma unroll
                for (int fi = 0; fi < 2; ++fi)
                    #pragma unroll
                    for (int fj = 0; fj < 2; ++fj)
                        acc[fi][fj] = __builtin_amdgcn_mfma_f32_16x16x32_fp8_fp8(
                            fx[cur][fi][h][p], fy[cur][fj][h][p], acc[fi][fj], 0, 0, 0);

        // epilogue on SQUARED distances; norms from LDS; NO shfl, NO branch
        float y2v[2];
        y2v[0] = y2s[b][l15];
        y2v[1] = y2s[b][16 + l15];
        float fm[2] = {INF, INF};
        #pragma unroll
        for (int fi = 0; fi < 2; ++fi) {
            const f32x4 x2v = *(const f32x4*)&x2s[b][wave * 32 + fi * 16 + quad * 4];
            #pragma unroll
            for (int fj = 0; fj < 2; ++fj)
                #pragma unroll
                for (int e = 0; e < 4; ++e) {
                    float sqv = fmaf(-2.0f, acc[fi][fj][e], x2v[e] + y2v[fj]);
                    bmin[fi][fj][e] = fminf(bmin[fi][fj][e], sqv);
                    fm[fj]          = fminf(fm[fj], sqv);
                }
        }
        #pragma unroll
        for (int fj = 0; fj < 2; ++fj) {
            // 4 quads same address: no-return ds_min, pipelined, no chain
            atomicMin(&fbuf[b][fj * 16 + l15],
                      __float_as_uint(fmaxf(fm[fj], 0.0f)));
        }
    }
    __syncthreads();  // all waves' fbuf contributions visible

    // flush forward mins: 256 entries, one per thread (relaxed device atomics)
    {
        int b = tid >> 5, c = tid & 31;
        atomicMin(&fwd[(size_t)b * MM + m0 + c], fbuf[b][c]);
    }

    // backward: sqrt(clamp(min-over-b)), block-reduce, ONE plain store/block
    float s = 0.0f;
    #pragma unroll
    for (int fi = 0; fi < 2; ++fi)
        #pragma unroll
        for (int fj = 0; fj < 2; ++fj)
            #pragma unroll
            for (int e = 0; e < 4; ++e)
                s += sqrtf(fmaxf(bmin[fi][fj][e], 0.0f));
    #pragma unroll
    for (int off = 32; off; off >>= 1) s += __shfl_down(s, off, 64);
    if (lane == 0) red[wave] = s;
    __syncthreads();
    if (tid == 0) bpart[id] = red[0] + red[1] + red[2] + red[3];
}

// Finalize: 32 blocks x 256 threads. fwd: one uint4/thread; bpart: one/thread.
// The (cheap, 32x) device fences live HERE, not in the 4096-block main.
__global__ __launch_bounds__(256)
void finalize_kernel(const unsigned int* __restrict__ fwd,
                     const float* __restrict__ bpart,
                     float* __restrict__ bsum, float* __restrict__ fsum,
                     unsigned int* __restrict__ counter, float* __restrict__ out) {
    __shared__ float redf[4], redb[4];
    __shared__ int isLast;
    const int tid = threadIdx.x, lane = tid & 63, wave = tid >> 6;
    const int gtid = blockIdx.x * 256 + tid;
    uint4 u = ((const uint4*)fwd)[gtid];
    float sf = sqrtf(__uint_as_float(u.x)) + sqrtf(__uint_as_float(u.y)) +
               sqrtf(__uint_as_float(u.z)) + sqrtf(__uint_as_float(u.w));
    float sb = (gtid < 4096) ? bpart[gtid] : 0.0f;
    #pragma unroll
    for (int off = 32; off; off >>= 1) {
        sf += __shfl_down(sf, off, 64);
        sb += __shfl_down(sb, off, 64);
    }
    if (lane == 0) { redf[wave] = sf; redb[wave] = sb; }
    __syncthreads();
    if (tid == 0) {
        atomicAdd(fsum, redf[0] + redf[1] + redf[2] + redf[3]);
        atomicAdd(bsum, redb[0] + redb[1] + redb[2] + redb[3]);
        __threadfence();
        unsigned int c = atomicAdd(counter, 1u);
        isLast = (c == gridDim.x - 1) ? 1 : 0;
        if (isLast) {
            __threadfence();
            float fs = __hip_atomic_load(fsum, __ATOMIC_RELAXED,
                                         __HIP_MEMORY_SCOPE_AGENT);
            float bs = __hip_atomic_load(bsum, __ATOMIC_RELAXED,
                                         __HIP_MEMORY_SCOPE_AGENT);
            out[0] = fs / (float)(BB * MM) + bs / ((float)NN * (float)MM);
        }
    }
}

extern "C" void kernel_launch(void* const* d_in, const int* in_sizes, int n_in,
                              void* d_out, int out_size, void* d_ws, size_t ws_size,
                              hipStream_t stream) {
    const float* x = (const float*)d_in[0];  // (B,N,D)
    const float* y = (const float*)d_in[1];  // (B,M,D)
    float* out = (float*)d_out;

    char* w = (char*)d_ws;
    unsigned char* xq = (unsigned char*)(w);               // 4 MB fp8 (frag order)
    unsigned char* yq = (unsigned char*)(w + 4194304);     // 4 MB fp8 (frag order)
    float*    x2 = (float*)(w + 8388608);                  // 128 KB
    float*    y2 = (float*)(w + 8519680);                  // 128 KB
    unsigned int* fwd = (unsigned int*)(w + 8650752);      // 128 KB
    float*    bpart = (float*)(w + 8781824);               // 16 KB
    float*    bsum = (float*)(w + 8798208);                // 4 B
    float*    fsum = (float*)(w + 8798212);                // 4 B
    unsigned int* counter = (unsigned int*)(w + 8798216);  // 4 B

    // 65536 rows, one per 32 lanes -> 2M threads
    prep_all<<<(2 * BB * NN * 32) / 256, 256, 0, stream>>>(x, y, xq, yq, x2, y2,
                                                           fwd, bsum, fsum, counter);
    chamfer_main<<<4096, 256, 0, stream>>>(xq, yq, x2, y2, fwd, bpart);
    finalize_kernel<<<32, 256, 0, stream>>>(fwd, bpart, bsum, fsum, counter, out);
}